// Round 6
// baseline (188.362 us; speedup 1.0000x reference)
//
#include <hip/hip_runtime.h>

// DetectionLoss: B=32768, G=7, A=2, C=3, M=20.
// R6: ONE load exposure per wave.
// R2-R5 post-mortem: all variants ~60us regardless of HBM vs LLC residency ->
// latency-chain bound: 7 serial K-iterations per wave, loads sunk to uses,
// ~2 blocks/CU resident. Fix: 1 cell per thread. Block = 512 thr = 5 batches
// (490 cells, 100 targets); phase 2 = 2 back-to-back float4 loads, single
// latency exposure; 6554 blocks (~26/CU of work, 4 resident = 32 waves/CU).
//  - Phase 1: per-target assignment into LDS (100 threads).
//  - Phase 1b: last-write-wins winner test, direct race-free table write.
//  - Phase 2: branchless; negatives broadcast-read zero slot; sp(-x)=sp(x)-x.
//  - Partials AoS [nblocks][8] plain stores (no global atomics, per R1 pm),
//    1024-thread reduce kernel (coalesced float4 pairs, ~7 short iters).

namespace {
constexpr int kG = 7;
constexpr int kA = 2;
constexpr int kM = 20;
constexpr int kCells = kG * kG * kA;     // 98
constexpr int kCh = 8;                   // 5 + C
constexpr int kNBatch = 5;               // batches per block
constexpr int kBlock = 512;              // 8 waves
constexpr int kTgtB = kNBatch * kM;      // 100
constexpr int kCellsB = kNBatch * kCells;// 490 active cells (22 idle lanes)
}

__device__ __forceinline__ float softplus_fast(float x) {
    // logaddexp(x,0); fast exp/log — validated absmax 0.0 in R2-R5
    return fmaxf(x, 0.0f) + __logf(1.0f + __expf(-fabsf(x)));
}

__global__ __launch_bounds__(kBlock) void det_loss_main(
    const float* __restrict__ preds,
    const float* __restrict__ tboxes,
    const int* __restrict__ tlabels,
    const int* __restrict__ nobjs,
    const float* __restrict__ anchors,
    const float* __restrict__ cweights,
    float* __restrict__ partial,   // AoS [gridDim.x][8]: obj,noobj,bbox,cls,npos,0,0,0
    int B)
{
    __shared__ float4 s_tv[kTgtB + 1];   // slot kTgtB = zeros (negative broadcast)
    __shared__ float  s_cw[kTgtB + 1];
    __shared__ int    s_lab[kTgtB + 1];
    __shared__ short  s_cell[kTgtB];     // block-local cell = bl*98+c, -1 invalid
    __shared__ short  s_table[kCellsB];  // cell -> winning target idx, -1 none
    __shared__ float  s_red[kBlock / 64][5];

    const int tid = threadIdx.x;
    const int b0 = blockIdx.x * kNBatch;
    const int nAct = min(kNBatch, B - b0) * kCells;

    if (tid < kCellsB) s_table[tid] = -1;
    if (tid == kBlock - 1) {
        s_tv[kTgtB] = make_float4(0.f, 0.f, 0.f, 0.f);
        s_cw[kTgtB] = 0.f;
        s_lab[kTgtB] = 0;
    }

    const float a00 = anchors[0], a01 = anchors[1];
    const float a10 = anchors[2], a11 = anchors[3];

    // ---- Phase 1: per-target assignment (100 threads, 1 iter) ----
    if (tid < kTgtB) {
        const int bl = tid / kM;
        const int m  = tid - bl * kM;
        const int b  = b0 + bl;
        short cell = -1;
        float4 tv = make_float4(0.f, 0.f, 0.f, 0.f);
        float cwv = 0.f;
        int lab = 0;
        if (b < B && m < nobjs[b]) {
            const float4 box = ((const float4*)tboxes)[(size_t)b * kM + m];
            const float x1 = box.x, y1 = box.y, x2 = box.z, y2 = box.w;
            const float cx = (x1 + x2) * 0.5f, cy = (y1 + y2) * 0.5f;
            const float w = x2 - x1, h = y2 - y1;
            if (w > 0.f && h > 0.f) {
                const int gi = min(max((int)floorf(cy * (float)kG), 0), kG - 1);
                const int gj = min(max((int)floorf(cx * (float)kG), 0), kG - 1);
                const float wg = w * (float)kG, hg = h * (float)kG;
                const float i0 = fminf(wg, a00) * fminf(hg, a01);
                const float u0 = wg * hg + a00 * a01 - i0;
                const float r0 = i0 / (u0 + 1e-6f);
                const float i1 = fminf(wg, a10) * fminf(hg, a11);
                const float u1 = wg * hg + a10 * a11 - i1;
                const float r1 = i1 / (u1 + 1e-6f);
                const int a = (r1 > r0) ? 1 : 0;   // argmax, first-max wins
                const float aw = a ? a10 : a00;
                const float ah = a ? a11 : a01;
                tv.x = cx * (float)kG - (float)gj;
                tv.y = cy * (float)kG - (float)gi;
                tv.z = __logf(fmaxf(wg, 0.01f) / (aw + 1e-6f));
                tv.w = __logf(fmaxf(hg, 0.01f) / (ah + 1e-6f));
                cell = (short)(bl * kCells + (gi * kG + gj) * kA + a);
                lab = tlabels[(size_t)b * kM + m];
                cwv = cweights[lab];
            }
        }
        s_cell[tid] = cell;
        s_tv[tid] = tv;
        s_cw[tid] = cwv;
        s_lab[tid] = lab;
    }
    __syncthreads();

    // ---- Phase 1b: winner test -> direct table write (race-free) ----
    if (tid < kTgtB) {
        const short c = s_cell[tid];
        if (c >= 0) {
            const int bl = tid / kM;
            const int m  = tid - bl * kM;
            bool win = true;
            for (int m2 = m + 1; m2 < kM; ++m2) {
                if (s_cell[bl * kM + m2] == c) { win = false; break; }
            }
            if (win) s_table[c] = (short)tid;   // unique winner per cell
        }
    }
    __syncthreads();

    // ---- Phase 2: one cell per thread, branchless ----
    float accO = 0.f, accN = 0.f, accB = 0.f, accC = 0.f, npf = 0.f;
    if (tid < nAct) {
        const float4* __restrict__ pc =
            (const float4*)preds + ((size_t)b0 * kCells + tid) * 2;
        const float4 p0 = pc[0];
        const float4 p1 = pc[1];
        const int j = s_table[tid];
        const bool pos = (j >= 0);
        const int jj = pos ? j : kTgtB;
        const float m = pos ? 1.f : 0.f;
        const float4 tv = s_tv[jj];
        const float cwv = s_cw[jj];
        const int lab = s_lab[jj];

        const float po = p0.x;
        const float spo = softplus_fast(po);
        accN = spo - m * spo;              // (1-m)*sp(po)
        accO = m * (spo - po);             // m*sp(-po)

        float d, ad, sb;
        d = p0.y - tv.x; ad = fabsf(d); sb  = (ad < 1.f) ? 0.5f * d * d : ad - 0.5f;
        d = p0.z - tv.y; ad = fabsf(d); sb += (ad < 1.f) ? 0.5f * d * d : ad - 0.5f;
        d = p0.w - tv.z; ad = fabsf(d); sb += (ad < 1.f) ? 0.5f * d * d : ad - 0.5f;
        d = p1.x - tv.w; ad = fabsf(d); sb += (ad < 1.f) ? 0.5f * d * d : ad - 0.5f;
        accB = m * sb;

        const float c0 = p1.y, c1 = p1.z, c2 = p1.w;
        const float mx = fmaxf(c0, fmaxf(c1, c2));
        const float lse = mx + __logf(__expf(c0 - mx) + __expf(c1 - mx) + __expf(c2 - mx));
        const float logit = (lab == 0) ? c0 : ((lab == 1) ? c1 : c2);
        accC = m * cwv * (lse - logit);
        npf = m;
    }

    // ---- Block reduce + plain AoS stores ----
    float vals[5] = {accO, accN, accB, accC, npf};
    #pragma unroll
    for (int k = 0; k < 5; ++k) {
        float v = vals[k];
        #pragma unroll
        for (int off = 32; off > 0; off >>= 1) v += __shfl_down(v, off, 64);
        vals[k] = v;
    }
    const int wave = tid >> 6;
    const int lane = tid & 63;
    if (lane == 0) {
        #pragma unroll
        for (int k = 0; k < 5; ++k) s_red[wave][k] = vals[k];
    }
    __syncthreads();
    if (tid == 0) {
        float t[5];
        #pragma unroll
        for (int k = 0; k < 5; ++k) {
            float s = 0.f;
            #pragma unroll
            for (int w = 0; w < kBlock / 64; ++w) s += s_red[w][k];
            t[k] = s;
        }
        float4* p4o = (float4*)(partial + (size_t)blockIdx.x * 8);
        p4o[0] = make_float4(t[0], t[1], t[2], t[3]);
        p4o[1] = make_float4(t[4], 0.f, 0.f, 0.f);
    }
}

__global__ __launch_bounds__(1024) void det_loss_reduce(
    const float* __restrict__ partial, int nblocks, float* __restrict__ out)
{
    __shared__ float s_red[16][5];
    const int tid = threadIdx.x;
    const float4* __restrict__ p4 = (const float4*)partial;
    float v[5] = {0.f, 0.f, 0.f, 0.f, 0.f};
    for (int e = tid; e < nblocks; e += 1024) {
        const float4 a = p4[2 * e];
        const float4 b = p4[2 * e + 1];
        v[0] += a.x; v[1] += a.y; v[2] += a.z; v[3] += a.w; v[4] += b.x;
    }
    #pragma unroll
    for (int k = 0; k < 5; ++k) {
        float x = v[k];
        #pragma unroll
        for (int off = 32; off > 0; off >>= 1) x += __shfl_down(x, off, 64);
        v[k] = x;
    }
    const int wave = tid >> 6;
    const int lane = tid & 63;
    if (lane == 0) {
        #pragma unroll
        for (int k = 0; k < 5; ++k) s_red[wave][k] = v[k];
    }
    __syncthreads();
    if (tid == 0) {
        float t[5];
        #pragma unroll
        for (int k = 0; k < 5; ++k) {
            float s = 0.f;
            #pragma unroll
            for (int w = 0; w < 16; ++w) s += s_red[w][k];
            t[k] = s;
        }
        const float npv = fmaxf(t[4], 1.0f);
        out[0] = (5.0f * t[2] + 1.0f * t[0] + 0.5f * t[1] + 2.0f * t[3]) / npv;
    }
}

extern "C" void kernel_launch(void* const* d_in, const int* in_sizes, int n_in,
                              void* d_out, int out_size, void* d_ws, size_t ws_size,
                              hipStream_t stream) {
    const float* preds    = (const float*)d_in[0];
    const float* tboxes   = (const float*)d_in[1];
    const int*   tlabels  = (const int*)d_in[2];
    const int*   nobjs    = (const int*)d_in[3];
    const float* anchors  = (const float*)d_in[4];
    const float* cweights = (const float*)d_in[5];
    float* out = (float*)d_out;
    float* partial = (float*)d_ws;   // [nblocks][8], fully overwritten every call

    const int B = in_sizes[0] / (kCells * kCh);   // /784
    const int blocks = (B + kNBatch - 1) / kNBatch;

    det_loss_main<<<blocks, kBlock, 0, stream>>>(
        preds, tboxes, tlabels, nobjs, anchors, cweights, partial, B);
    det_loss_reduce<<<1, 1024, 0, stream>>>(partial, blocks, out);
}

// Round 7
// 188.014 us; speedup vs baseline: 1.0019x; 1.0019x over previous
//
#include <hip/hip_runtime.h>

// DetectionLoss: B=32768, G=7, A=2, C=3, M=20.
// R7: decompose the monolithic kernel to separate "structure" from "position".
// R2-R6 post-mortem: five different monolithic structures all pinned at
// ~55-66us (incl. LLC-warm with FETCH~0), though per-CU resource accounting
// predicts 10-20us. This round:
//   A) det_assign: build GLOBAL cell->m table (short, -1 none) + 32B per-target
//      records. Tiny (~28MB traffic). Runs first (absorbs any post-fill
//      positional penalty if that theory is right).
//   B) det_stream: pure streaming - one cell per thread, NO barriers before
//      reduce, coalesced short + 2x float4 loads, conditional record gather
//      (~10% lanes, LLC-hot). 12544 blocks.
//   C) det_reduce: sum 12544 partials.
// No global atomics anywhere (R1 post-mortem).

namespace {
constexpr int kG = 7;
constexpr int kA = 2;
constexpr int kM = 20;
constexpr int kCells = kG * kG * kA;   // 98
constexpr int kCh = 8;                 // 5 + C
constexpr int kABat = 32;              // batches per assign-block
constexpr int kABlock = kABat * kM;    // 640 threads, one per target
constexpr int kBBlock = 256;           // stream block
}

__device__ __forceinline__ float softplus_fast(float x) {
    // logaddexp(x,0); fast exp/log — validated absmax 0.0 in R2-R6
    return fmaxf(x, 0.0f) + __logf(1.0f + __expf(-fabsf(x)));
}

// ---- A: per-target assignment -> global table + records ----
__global__ __launch_bounds__(kABlock) void det_assign(
    const float* __restrict__ tboxes,
    const int* __restrict__ tlabels,
    const int* __restrict__ nobjs,
    const float* __restrict__ anchors,
    const float* __restrict__ cweights,
    short* __restrict__ table,      // [B*98] winning m, -1 none
    float4* __restrict__ rec,       // [B*20][2]: {tv}, {cw, labf, 0, 0}
    int B)
{
    __shared__ short s_cell[kABlock];   // per-target cell c in [0,98), -1 invalid

    const int tid = threadIdx.x;
    const int b0 = blockIdx.x * kABat;

    // init this block's table slice to -1 (2 shorts per int store)
    {
        int* tp = (int*)(table + (size_t)b0 * kCells);
        const int nInt = kABat * kCells / 2;   // 1568
        for (int i = tid; i < nInt; i += kABlock) tp[i] = -1;  // 0xFFFFFFFF
    }

    const float a00 = anchors[0], a01 = anchors[1];
    const float a10 = anchors[2], a11 = anchors[3];

    const int bl = tid / kM;
    const int m  = tid - bl * kM;
    const int b  = b0 + bl;

    short cell = -1;
    float4 tv = make_float4(0.f, 0.f, 0.f, 0.f);
    float cwv = 0.f;
    float labf = 0.f;
    if (b < B && m < nobjs[b]) {
        const float4 box = ((const float4*)tboxes)[(size_t)b * kM + m];
        const float x1 = box.x, y1 = box.y, x2 = box.z, y2 = box.w;
        const float cx = (x1 + x2) * 0.5f, cy = (y1 + y2) * 0.5f;
        const float w = x2 - x1, h = y2 - y1;
        if (w > 0.f && h > 0.f) {
            const int gi = min(max((int)floorf(cy * (float)kG), 0), kG - 1);
            const int gj = min(max((int)floorf(cx * (float)kG), 0), kG - 1);
            const float wg = w * (float)kG, hg = h * (float)kG;
            const float i0 = fminf(wg, a00) * fminf(hg, a01);
            const float u0 = wg * hg + a00 * a01 - i0;
            const float r0 = i0 / (u0 + 1e-6f);
            const float i1 = fminf(wg, a10) * fminf(hg, a11);
            const float u1 = wg * hg + a10 * a11 - i1;
            const float r1 = i1 / (u1 + 1e-6f);
            const int a = (r1 > r0) ? 1 : 0;      // argmax, first-max wins
            const float aw = a ? a10 : a00;
            const float ah = a ? a11 : a01;
            tv.x = cx * (float)kG - (float)gj;
            tv.y = cy * (float)kG - (float)gi;
            tv.z = __logf(fmaxf(wg, 0.01f) / (aw + 1e-6f));
            tv.w = __logf(fmaxf(hg, 0.01f) / (ah + 1e-6f));
            cell = (short)((gi * kG + gj) * kA + a);
            const int lab = tlabels[(size_t)b * kM + m];
            cwv = cweights[lab];
            labf = (float)lab;
        }
    }
    s_cell[tid] = cell;
    if (b < B) {
        rec[((size_t)b * kM + m) * 2]     = tv;
        rec[((size_t)b * kM + m) * 2 + 1] = make_float4(cwv, labf, 0.f, 0.f);
    }
    __syncthreads();

    // last-write-wins winner test: no LATER same-batch target in same cell
    if (cell >= 0) {
        bool win = true;
        const int base = bl * kM;
        for (int m2 = m + 1; m2 < kM; ++m2) {
            if (s_cell[base + m2] == cell) { win = false; break; }
        }
        if (win) table[(size_t)b * kCells + cell] = (short)m;  // unique per cell
    }
}

// ---- B: pure streaming loss ----
__global__ __launch_bounds__(kBBlock) void det_stream(
    const float* __restrict__ preds,
    const short* __restrict__ table,
    const float4* __restrict__ rec,
    float* __restrict__ partial,    // AoS [nblocks][8]
    int ncells)
{
    __shared__ float s_red[kBBlock / 64][5];

    const int tid = threadIdx.x;
    const int g = blockIdx.x * kBBlock + tid;

    float accO = 0.f, accN = 0.f, accB = 0.f, accC = 0.f, npf = 0.f;
    if (g < ncells) {
        const float4* __restrict__ pc = (const float4*)preds + (size_t)g * 2;
        const float4 p0 = pc[0];
        const float4 p1 = pc[1];
        const int t = table[g];            // sign-extended short
        const bool pos = (t >= 0);

        float4 tv = make_float4(0.f, 0.f, 0.f, 0.f);
        float4 r2 = make_float4(0.f, 0.f, 0.f, 0.f);
        if (pos) {
            const unsigned b = (unsigned)g / (unsigned)kCells;
            const float4* rp = rec + ((size_t)b * kM + t) * 2;
            tv = rp[0];
            r2 = rp[1];
        }
        const float m = pos ? 1.f : 0.f;

        const float po = p0.x;
        const float spo = softplus_fast(po);
        accN = spo - m * spo;              // (1-m)*sp(po)
        accO = m * (spo - po);             // m*sp(-po)

        float d, ad, sb;
        d = p0.y - tv.x; ad = fabsf(d); sb  = (ad < 1.f) ? 0.5f * d * d : ad - 0.5f;
        d = p0.z - tv.y; ad = fabsf(d); sb += (ad < 1.f) ? 0.5f * d * d : ad - 0.5f;
        d = p0.w - tv.z; ad = fabsf(d); sb += (ad < 1.f) ? 0.5f * d * d : ad - 0.5f;
        d = p1.x - tv.w; ad = fabsf(d); sb += (ad < 1.f) ? 0.5f * d * d : ad - 0.5f;
        accB = m * sb;

        const int lab = (int)r2.y;
        const float c0 = p1.y, c1 = p1.z, c2 = p1.w;
        const float mx = fmaxf(c0, fmaxf(c1, c2));
        const float lse = mx + __logf(__expf(c0 - mx) + __expf(c1 - mx) + __expf(c2 - mx));
        const float logit = (lab == 0) ? c0 : ((lab == 1) ? c1 : c2);
        accC = m * r2.x * (lse - logit);
        npf = m;
    }

    float vals[5] = {accO, accN, accB, accC, npf};
    #pragma unroll
    for (int k = 0; k < 5; ++k) {
        float v = vals[k];
        #pragma unroll
        for (int off = 32; off > 0; off >>= 1) v += __shfl_down(v, off, 64);
        vals[k] = v;
    }
    const int wave = tid >> 6;
    const int lane = tid & 63;
    if (lane == 0) {
        #pragma unroll
        for (int k = 0; k < 5; ++k) s_red[wave][k] = vals[k];
    }
    __syncthreads();
    if (tid == 0) {
        float t[5];
        #pragma unroll
        for (int k = 0; k < 5; ++k) {
            float s = 0.f;
            #pragma unroll
            for (int w = 0; w < kBBlock / 64; ++w) s += s_red[w][k];
            t[k] = s;
        }
        float4* p4o = (float4*)(partial + (size_t)blockIdx.x * 8);
        p4o[0] = make_float4(t[0], t[1], t[2], t[3]);
        p4o[1] = make_float4(t[4], 0.f, 0.f, 0.f);
    }
}

__global__ __launch_bounds__(1024) void det_reduce(
    const float* __restrict__ partial, int nblocks, float* __restrict__ out)
{
    __shared__ float s_red[16][5];
    const int tid = threadIdx.x;
    const float4* __restrict__ p4 = (const float4*)partial;
    float v[5] = {0.f, 0.f, 0.f, 0.f, 0.f};
    for (int e = tid; e < nblocks; e += 1024) {
        const float4 a = p4[2 * e];
        const float4 b = p4[2 * e + 1];
        v[0] += a.x; v[1] += a.y; v[2] += a.z; v[3] += a.w; v[4] += b.x;
    }
    #pragma unroll
    for (int k = 0; k < 5; ++k) {
        float x = v[k];
        #pragma unroll
        for (int off = 32; off > 0; off >>= 1) x += __shfl_down(x, off, 64);
        v[k] = x;
    }
    const int wave = tid >> 6;
    const int lane = tid & 63;
    if (lane == 0) {
        #pragma unroll
        for (int k = 0; k < 5; ++k) s_red[wave][k] = v[k];
    }
    __syncthreads();
    if (tid == 0) {
        float t[5];
        #pragma unroll
        for (int k = 0; k < 5; ++k) {
            float s = 0.f;
            #pragma unroll
            for (int w = 0; w < 16; ++w) s += s_red[w][k];
            t[k] = s;
        }
        const float npv = fmaxf(t[4], 1.0f);
        out[0] = (5.0f * t[2] + 1.0f * t[0] + 0.5f * t[1] + 2.0f * t[3]) / npv;
    }
}

extern "C" void kernel_launch(void* const* d_in, const int* in_sizes, int n_in,
                              void* d_out, int out_size, void* d_ws, size_t ws_size,
                              hipStream_t stream) {
    const float* preds    = (const float*)d_in[0];
    const float* tboxes   = (const float*)d_in[1];
    const int*   tlabels  = (const int*)d_in[2];
    const int*   nobjs    = (const int*)d_in[3];
    const float* anchors  = (const float*)d_in[4];
    const float* cweights = (const float*)d_in[5];
    float* out = (float*)d_out;

    const int B = in_sizes[0] / (kCells * kCh);   // /784 = 32768
    const int ncells = B * kCells;                 // 3,211,264

    // d_ws layout (all 16B-aligned):
    //   table:   B*98 shorts               = 6,422,528 B
    //   rec:     B*20*32 B                 = 20,971,520 B
    //   partial: nSblocks*32 B
    char* ws = (char*)d_ws;
    short*  table   = (short*)ws;
    size_t  off     = (size_t)B * kCells * sizeof(short);   // 6,422,528 (16B-mult)
    float4* rec     = (float4*)(ws + off);
    off            += (size_t)B * kM * 2 * sizeof(float4);  // +20,971,520
    float*  partial = (float*)(ws + off);

    const int aBlocks = (B + kABat - 1) / kABat;            // 1024
    const int sBlocks = (ncells + kBBlock - 1) / kBBlock;   // 12544

    det_assign<<<aBlocks, kABlock, 0, stream>>>(
        tboxes, tlabels, nobjs, anchors, cweights, table, rec, B);
    det_stream<<<sBlocks, kBBlock, 0, stream>>>(
        preds, table, rec, partial, ncells);
    det_reduce<<<1, 1024, 0, stream>>>(partial, sBlocks, out);
}